// Round 1
// baseline (328.643 us; speedup 1.0000x reference)
//
#include <hip/hip_runtime.h>
#include <hip/hip_bf16.h>

// Kaldi polyphase resampler 16k -> 24k.
//   in_unit = 2 (conv stride), out_unit = 3 (phases), W = 13 taps,
//   first_indices = [-6, -5, -4]  (i.e. f[p] = p - 6)
// out[c][3u+p] = sum_j w[p][j] * x[c][2u + p - 6 + j], zero-padded x.
//
// Each block: 256 u-values (= 768 contiguous outputs) of one channel.
// LDS-stage the 2*256+15 = 527-float input window; each thread computes
// the 3 phases of one u from a shared 15-float register window.

#define NCH   8
#define TAPS  13
#define BLOCK 256

__global__ __launch_bounds__(BLOCK) void resample_kernel(
    const float* __restrict__ x,    // [NCH, L]
    const float* __restrict__ w,    // [3, TAPS]
    float* __restrict__ out,        // [NCH, tot]
    int L, int tot, int U)          // U = ceil(tot/3)
{
    __shared__ float sx[2 * BLOCK + 16];   // need 2*BLOCK+15 = 527
    __shared__ float sw[3][TAPS];

    const int tid = threadIdx.x;
    const int c   = blockIdx.y;
    const int u0  = blockIdx.x * BLOCK;
    const long g0 = 2L * u0 - 6;           // global x-index of sx[0]
    const float* xc = x + (long)c * L;

    if (tid < 3 * TAPS) sw[tid / TAPS][tid % TAPS] = w[tid];

    for (int s = tid; s < 2 * BLOCK + 15; s += BLOCK) {
        long idx = g0 + s;
        sx[s] = (idx >= 0 && idx < (long)L) ? xc[idx] : 0.0f;
    }
    __syncthreads();

    const int u = u0 + tid;
    if (u >= U) return;

    // Window covers x[2u-6 .. 2u+8]  ->  sx[2*tid .. 2*tid+14]
    float win[15];
#pragma unroll
    for (int j = 0; j < 15; ++j) win[j] = sx[2 * tid + j];

    float acc0 = 0.f, acc1 = 0.f, acc2 = 0.f;
#pragma unroll
    for (int j = 0; j < TAPS; ++j) {
        acc0 = fmaf(sw[0][j], win[j],     acc0);
        acc1 = fmaf(sw[1][j], win[j + 1], acc1);
        acc2 = fmaf(sw[2][j], win[j + 2], acc2);
    }

    const long t0 = 3L * u;
    float* oc = out + (long)c * tot;
    // tot may not be a multiple of 3 in general; guard the tail.
    oc[t0] = acc0;
    if (t0 + 1 < tot) oc[t0 + 1] = acc1;
    if (t0 + 2 < tot) oc[t0 + 2] = acc2;
}

extern "C" void kernel_launch(void* const* d_in, const int* in_sizes, int n_in,
                              void* d_out, int out_size, void* d_ws, size_t ws_size,
                              hipStream_t stream) {
    const float* x = (const float*)d_in[0];
    const float* w = (const float*)d_in[1];
    float* out     = (float*)d_out;

    const int L   = in_sizes[0] / NCH;     // 4,000,000
    const int tot = out_size / NCH;        // 6,000,000
    const int U   = (tot + 2) / 3;         // 2,000,000 u-values per channel

    dim3 grid((U + BLOCK - 1) / BLOCK, NCH);
    resample_kernel<<<grid, BLOCK, 0, stream>>>(x, w, out, L, tot, U);
}

// Round 2
// 314.034 us; speedup vs baseline: 1.0465x; 1.0465x over previous
//
#include <hip/hip_runtime.h>
#include <hip/hip_bf16.h>
#include <math.h>

// Kaldi polyphase resampler 16k -> 24k.
//   in_unit = 2 (conv stride), out_unit = 3 (phases), W = 13 taps,
//   first_indices = [-6, -5, -4]  (f[p] = p - 6)
// out[c][3u+p] = sum_j w[p][j] * x[c][2u + p - 6 + j], zero-padded x.
//
// R2 change: weights passed BY VALUE (host-computed, exact numpy-formula
// replica) -> land in SGPRs via kernarg s_load. R1 was LDS-issue-bound on
// 39 broadcast ds_read_b32 weight loads per thread (54 LDS reads * 5.8cyc
// * 977 waves/CU ~= 127us == measured 128us). Window reads forced to
// 8x ds_read_b64 via aligned float2 view.

#define NCH   8
#define TAPS  13
#define BLOCK 256

struct Taps {                    // 156 B kernarg, -> SGPRs
    float w[3][TAPS];
};

__global__ __launch_bounds__(BLOCK) void resample_kernel(
    const float* __restrict__ x,    // [NCH, L]
    float* __restrict__ out,        // [NCH, tot]
    Taps wt,
    int L, int tot, int U)          // U = ceil(tot/3)
{
    __shared__ float sx[2 * BLOCK + 16];   // need 2*BLOCK+15 = 527

    const int tid = threadIdx.x;
    const int c   = blockIdx.y;
    const int u0  = blockIdx.x * BLOCK;
    const long g0 = 2L * u0 - 6;           // global x-index of sx[0]
    const float* xc = x + (long)c * L;

    for (int s = tid; s < 2 * BLOCK + 15; s += BLOCK) {
        long idx = g0 + s;
        sx[s] = (idx >= 0 && idx < (long)L) ? xc[idx] : 0.0f;
    }
    __syncthreads();

    const int u = u0 + tid;
    if (u >= U) return;

    // Window covers x[2u-6 .. 2u+8] -> sx[2*tid .. 2*tid+14]; base is
    // 8B-aligned so read as 8x float2 (ds_read_b64).
    float win[16];
    const float2* sx2 = (const float2*)&sx[2 * tid];
#pragma unroll
    for (int k = 0; k < 8; ++k) {
        float2 v = sx2[k];
        win[2 * k]     = v.x;
        win[2 * k + 1] = v.y;
    }

    float acc0 = 0.f, acc1 = 0.f, acc2 = 0.f;
#pragma unroll
    for (int j = 0; j < TAPS; ++j) {
        acc0 = fmaf(wt.w[0][j], win[j],     acc0);
        acc1 = fmaf(wt.w[1][j], win[j + 1], acc1);
        acc2 = fmaf(wt.w[2][j], win[j + 2], acc2);
    }

    const long t0 = 3L * u;
    float* oc = out + (long)c * tot;
    oc[t0] = acc0;
    if (t0 + 1 < tot) oc[t0 + 1] = acc1;
    if (t0 + 2 < tot) oc[t0 + 2] = acc2;
}

// Host-side exact replica of reference _filters() weight math (float64,
// then cast to fp32). Runs once at graph capture; values baked into the
// captured kernarg. Matches the d_in[1] contents to within libm ULPs.
static void compute_weights(Taps* t) {
    const double ORIG = 16000.0, NEWF = 24000.0, LPFW = 6.0;
    const double cutoff = 0.99 * 0.5 * ORIG;          // 7920
    const double ww = LPFW / (2.0 * cutoff);
    for (int p = 0; p < 3; ++p) {
        double out_t = (double)p / NEWF;
        double min_idx = ceil((out_t - ww) * ORIG);   // -6, -5, -4
        for (int j = 0; j < TAPS; ++j) {
            double inp = min_idx + (double)j;
            double dt = inp / ORIG - out_t;
            double w = 0.0;
            if (fabs(dt) < ww)
                w = 0.5 * (1.0 + cos(2.0 * M_PI * cutoff / LPFW * dt));
            if (dt != 0.0)
                w *= sin(2.0 * M_PI * cutoff * dt) / (M_PI * dt);
            else
                w *= 2.0 * cutoff;
            w /= ORIG;
            t->w[p][j] = (float)w;
        }
    }
}

extern "C" void kernel_launch(void* const* d_in, const int* in_sizes, int n_in,
                              void* d_out, int out_size, void* d_ws, size_t ws_size,
                              hipStream_t stream) {
    const float* x = (const float*)d_in[0];
    float* out     = (float*)d_out;

    const int L   = in_sizes[0] / NCH;     // 4,000,000
    const int tot = out_size / NCH;        // 6,000,000
    const int U   = (tot + 2) / 3;         // 2,000,000 u-values per channel

    Taps wt;
    compute_weights(&wt);

    dim3 grid((U + BLOCK - 1) / BLOCK, NCH);
    resample_kernel<<<grid, BLOCK, 0, stream>>>(x, out, wt, L, tot, U);
}

// Round 3
// 287.353 us; speedup vs baseline: 1.1437x; 1.0929x over previous
//
#include <hip/hip_runtime.h>
#include <hip/hip_bf16.h>
#include <math.h>

// Kaldi polyphase resampler 16k -> 24k.
//   in_unit = 2, out_unit = 3 phases, W = 13 taps, f[p] = p - 6.
// out[c][3u+p] = sum_t w[p][t] * x[c][2u + p - 6 + t], zero-padded x.
//
// R3: raise per-thread grain to 12 consecutive outputs (4 u x 3 phases).
//   - 4x fewer waves (62.5K total, 244/CU) -> less per-CU LDS/VMEM issue
//   - window = 24 floats via 6x ds_read_b128 (base 32*lt B, aligned)
//   - stores = 3x float4 per thread (16B grain, contiguous per thread)
//   - staging via aligned float4 global loads
// R2 post-mortem: store scatter (48B-stride dword stores, 3x line touches)
// + per-CU LDS issue at 977 waves/CU kept it ~114us. Weights stay in
// SGPRs via by-value kernarg struct (R2's win, keep).

#define NCH   8
#define TAPS  13
#define BLOCK 256
#define OUTS_PER_THREAD 12              // 4 u-values x 3 phases
#define U_PER_BLOCK     (4 * BLOCK)     // 1024
#define SX_FLOATS       (8 * BLOCK + 24) // 2072: window base 8*lt, +24 span
#define SX_UNITS        (SX_FLOATS / 4)  // 518 float4 units

struct Taps { float w[3][TAPS]; };       // 156 B kernarg -> SGPRs

__global__ __launch_bounds__(BLOCK) void resample_kernel(
    const float* __restrict__ x,    // [NCH, L]
    float* __restrict__ out,        // [NCH, tot]
    Taps wt,
    int L, int tot)
{
    __shared__ float sx[SX_FLOATS + 8];

    const int lt = threadIdx.x;
    const int c  = blockIdx.y;
    const long base = 2048L * blockIdx.x - 8;   // x-index of sx[0]
    const float* xc = x + (long)c * L;

    // Stage 2072 floats: x[base .. base+2071], zero-padded outside [0,L).
    for (int s = lt; s < SX_UNITS; s += BLOCK) {
        long idx4 = base + 4L * s;
        float4 v;
        if (idx4 >= 0 && idx4 + 4 <= L) {
            v = *(const float4*)(xc + idx4);     // 16B-aligned (idx4 % 4 == 0)
        } else {
            float t[4];
#pragma unroll
            for (int j = 0; j < 4; ++j) {
                long idx = idx4 + j;
                t[j] = (idx >= 0 && idx < (long)L) ? xc[idx] : 0.0f;
            }
            v = make_float4(t[0], t[1], t[2], t[3]);
        }
        ((float4*)sx)[s] = v;
    }
    __syncthreads();

    const long gt = (long)blockIdx.x * BLOCK + lt;  // global thread in channel
    const long n0 = OUTS_PER_THREAD * gt;           // first output index
    if (n0 >= tot) return;

    // Window: x[2*(4gt) - 6 .. +20] = sx[8*lt .. 8*lt+23] shifted by +2
    // (sx[0] = x[base] = x[8*gt_block0 - 8]).  6x ds_read_b128.
    float win[24];
    const float4* sx4 = (const float4*)&sx[8 * lt];
#pragma unroll
    for (int k = 0; k < 6; ++k) {
        float4 v = sx4[k];
        win[4 * k]     = v.x;
        win[4 * k + 1] = v.y;
        win[4 * k + 2] = v.z;
        win[4 * k + 3] = v.w;
    }

    // acc[j][p] = out[n0 + 3j + p]; input offset m = 2j + p + 2.
    float acc[4][3];
#pragma unroll
    for (int j = 0; j < 4; ++j)
#pragma unroll
        for (int p = 0; p < 3; ++p) {
            float a = 0.f;
#pragma unroll
            for (int t = 0; t < TAPS; ++t)
                a = fmaf(wt.w[p][t], win[2 * j + p + 2 + t], a);
            acc[j][p] = a;
        }

    float* oc = out + (long)c * tot;
    if (n0 + OUTS_PER_THREAD <= tot) {
        float4* o4 = (float4*)(oc + n0);            // 48*gt B: 16B-aligned
        o4[0] = make_float4(acc[0][0], acc[0][1], acc[0][2], acc[1][0]);
        o4[1] = make_float4(acc[1][1], acc[1][2], acc[2][0], acc[2][1]);
        o4[2] = make_float4(acc[2][2], acc[3][0], acc[3][1], acc[3][2]);
    } else {
#pragma unroll
        for (int k = 0; k < OUTS_PER_THREAD; ++k)
            if (n0 + k < tot) oc[n0 + k] = acc[k / 3][k % 3];
    }
}

// Host-side exact replica of reference _filters() weight math (float64 ->
// fp32). Runs at capture time; baked into kernarg.
static void compute_weights(Taps* t) {
    const double ORIG = 16000.0, NEWF = 24000.0, LPFW = 6.0;
    const double cutoff = 0.99 * 0.5 * ORIG;          // 7920
    const double ww = LPFW / (2.0 * cutoff);
    for (int p = 0; p < 3; ++p) {
        double out_t = (double)p / NEWF;
        double min_idx = ceil((out_t - ww) * ORIG);   // -6, -5, -4
        for (int j = 0; j < TAPS; ++j) {
            double inp = min_idx + (double)j;
            double dt = inp / ORIG - out_t;
            double w = 0.0;
            if (fabs(dt) < ww)
                w = 0.5 * (1.0 + cos(2.0 * M_PI * cutoff / LPFW * dt));
            if (dt != 0.0)
                w *= sin(2.0 * M_PI * cutoff * dt) / (M_PI * dt);
            else
                w *= 2.0 * cutoff;
            w /= ORIG;
            t->w[p][j] = (float)w;
        }
    }
}

extern "C" void kernel_launch(void* const* d_in, const int* in_sizes, int n_in,
                              void* d_out, int out_size, void* d_ws, size_t ws_size,
                              hipStream_t stream) {
    const float* x = (const float*)d_in[0];
    float* out     = (float*)d_out;

    const int L   = in_sizes[0] / NCH;     // 4,000,000
    const int tot = out_size / NCH;        // 6,000,000

    Taps wt;
    compute_weights(&wt);

    const int outs_per_block = BLOCK * OUTS_PER_THREAD;   // 3072
    dim3 grid((tot + outs_per_block - 1) / outs_per_block, NCH);
    resample_kernel<<<grid, BLOCK, 0, stream>>>(x, out, wt, L, tot);
}

// Round 4
// 281.704 us; speedup vs baseline: 1.1666x; 1.0201x over previous
//
#include <hip/hip_runtime.h>
#include <hip/hip_bf16.h>
#include <math.h>

// Kaldi polyphase resampler 16k -> 24k.
//   in_unit = 2, out_unit = 3 phases, W = 13 taps, f[p] = p - 6.
// out[c][3u+p] = sum_t w[p][t] * x[c][2u + p - 6 + t], zero-padded x.
//
// R4: LDS store-transpose. R3's stores were 3x float4 at 48B/lane stride
// (~144 line-segments per wave vs 48 minimal -> ~39us excess VMEM issue).
// Now: compute (unchanged, SGPR weights) -> write 12 results to sout at
// byte 48*lt (bank-conflict-free: bases cover all 32 banks once per 8
// lanes) -> barrier -> read back contiguous float4 -> fully coalesced
// global store (16 segments/wave-store, minimal).

#define NCH   8
#define TAPS  13
#define BLOCK 256
#define OUTS_PER_THREAD 12               // 4 u-values x 3 phases
#define OUTS_PER_BLOCK  (BLOCK * OUTS_PER_THREAD)   // 3072
#define SX_FLOATS       (8 * BLOCK + 24) // 2072: window base 8*lt, +24 span
#define SX_UNITS        (SX_FLOATS / 4)  // 518 float4 units

struct Taps { float w[3][TAPS]; };       // 156 B kernarg -> SGPRs

__global__ __launch_bounds__(BLOCK) void resample_kernel(
    const float* __restrict__ x,    // [NCH, L]
    float* __restrict__ out,        // [NCH, tot]
    Taps wt,
    int L, int tot)
{
    __shared__ __attribute__((aligned(16))) float sx[SX_FLOATS + 8];
    __shared__ __attribute__((aligned(16))) float sout[OUTS_PER_BLOCK];

    const int lt = threadIdx.x;
    const int c  = blockIdx.y;
    const long B0   = (long)OUTS_PER_BLOCK * blockIdx.x;  // channel-local out
    const long base = 2048L * blockIdx.x - 8;             // x-index of sx[0]
    const float* xc = x + (long)c * L;

    // Stage 2072 floats: x[base .. base+2071], zero-padded outside [0,L).
    for (int s = lt; s < SX_UNITS; s += BLOCK) {
        long idx4 = base + 4L * s;
        float4 v;
        if (idx4 >= 0 && idx4 + 4 <= L) {
            v = *(const float4*)(xc + idx4);     // 16B-aligned (idx4 % 4 == 0)
        } else {
            float t[4];
#pragma unroll
            for (int j = 0; j < 4; ++j) {
                long idx = idx4 + j;
                t[j] = (idx >= 0 && idx < (long)L) ? xc[idx] : 0.0f;
            }
            v = make_float4(t[0], t[1], t[2], t[3]);
        }
        ((float4*)sx)[s] = v;
    }
    __syncthreads();

    // Window: sx[8*lt .. 8*lt+23] via 6x ds_read_b128.
    float win[24];
    const float4* sx4 = (const float4*)&sx[8 * lt];
#pragma unroll
    for (int k = 0; k < 6; ++k) {
        float4 v = sx4[k];
        win[4 * k]     = v.x;
        win[4 * k + 1] = v.y;
        win[4 * k + 2] = v.z;
        win[4 * k + 3] = v.w;
    }

    // acc[j][p] = output (B0 + 12*lt + 3j + p); input offset m = 2j + p + 2.
    float acc[4][3];
#pragma unroll
    for (int j = 0; j < 4; ++j)
#pragma unroll
        for (int p = 0; p < 3; ++p) {
            float a = 0.f;
#pragma unroll
            for (int t = 0; t < TAPS; ++t)
                a = fmaf(wt.w[p][t], win[2 * j + p + 2 + t], a);
            acc[j][p] = a;
        }

    // Transpose through LDS: write 12 results at byte 48*lt (conflict-free).
    float4* so4 = (float4*)&sout[12 * lt];
    so4[0] = make_float4(acc[0][0], acc[0][1], acc[0][2], acc[1][0]);
    so4[1] = make_float4(acc[1][1], acc[1][2], acc[2][0], acc[2][1]);
    so4[2] = make_float4(acc[2][2], acc[3][0], acc[3][1], acc[3][2]);
    __syncthreads();

    // Coalesced store: store k, lane lt -> outputs B0 + 1024k + 4lt ..+3.
    float* oc = out + (long)c * tot;
#pragma unroll
    for (int k = 0; k < 3; ++k) {
        long g = B0 + 1024L * k + 4 * lt;
        float4 v = ((const float4*)sout)[256 * k + lt];
        if (g + 4 <= (long)tot) {
            *(float4*)(oc + g) = v;
        } else if (g < (long)tot) {
            const float vv[4] = {v.x, v.y, v.z, v.w};
            for (int e = 0; e < 4 && g + e < (long)tot; ++e)
                oc[g + e] = vv[e];
        }
    }
}

// Host-side exact replica of reference _filters() weight math (float64 ->
// fp32). Runs at capture time; baked into kernarg.
static void compute_weights(Taps* t) {
    const double ORIG = 16000.0, NEWF = 24000.0, LPFW = 6.0;
    const double cutoff = 0.99 * 0.5 * ORIG;          // 7920
    const double ww = LPFW / (2.0 * cutoff);
    for (int p = 0; p < 3; ++p) {
        double out_t = (double)p / NEWF;
        double min_idx = ceil((out_t - ww) * ORIG);   // -6, -5, -4
        for (int j = 0; j < TAPS; ++j) {
            double inp = min_idx + (double)j;
            double dt = inp / ORIG - out_t;
            double w = 0.0;
            if (fabs(dt) < ww)
                w = 0.5 * (1.0 + cos(2.0 * M_PI * cutoff / LPFW * dt));
            if (dt != 0.0)
                w *= sin(2.0 * M_PI * cutoff * dt) / (M_PI * dt);
            else
                w *= 2.0 * cutoff;
            w /= ORIG;
            t->w[p][j] = (float)w;
        }
    }
}

extern "C" void kernel_launch(void* const* d_in, const int* in_sizes, int n_in,
                              void* d_out, int out_size, void* d_ws, size_t ws_size,
                              hipStream_t stream) {
    const float* x = (const float*)d_in[0];
    float* out     = (float*)d_out;

    const int L   = in_sizes[0] / NCH;     // 4,000,000
    const int tot = out_size / NCH;        // 6,000,000

    Taps wt;
    compute_weights(&wt);

    dim3 grid((tot + OUTS_PER_BLOCK - 1) / OUTS_PER_BLOCK, NCH);
    resample_kernel<<<grid, BLOCK, 0, stream>>>(x, out, wt, L, tot);
}